// Round 4
// baseline (101.655 us; speedup 1.0000x reference)
//
#include <hip/hip_runtime.h>
#include <cstdint>

#define B_ 8
#define T_ 2048
#define C_ 1024
#define H_ 64
#define BT_ (B_ * T_)

typedef short short8 __attribute__((ext_vector_type(8)));
typedef float f32x4 __attribute__((ext_vector_type(4)));

__device__ inline short f2bf(float f) {
  uint32_t u = __float_as_uint(f);
  u += 0x7fffu + ((u >> 16) & 1u);  // RNE; inputs finite
  return (short)(u >> 16);
}

// ---------------------------------------------------------------------------
// prep_w: Wk/Wq/Wv [1024][64] fp32 -> Wt [192][1024] bf16 (transposed).
// The attention score scale 1024^-0.5 = 2^-5 is folded into Wk here (exact
// exponent shift in fp32; queries = x@Wk per the source quirk).
// ---------------------------------------------------------------------------
__global__ __launch_bounds__(256) void prep_w(
    const float* __restrict__ Wk, const float* __restrict__ Wq,
    const float* __restrict__ Wv, short* __restrict__ Wt) {
  __shared__ float wl[64][68];
  const int mat = blockIdx.x >> 4;
  const int kc = blockIdx.x & 15;
  const float* W = (mat == 0) ? Wk : (mat == 1) ? Wq : Wv;
  const float sc = (mat == 0) ? 0.03125f : 1.0f;
  const int t = threadIdx.x;
  const int k0 = kc * 64;
#pragma unroll
  for (int j = 0; j < 4; ++j) {
    int s = t + 256 * j;
    int kr = s >> 4, cf = s & 15;
    float4 v = *reinterpret_cast<const float4*>(&W[(size_t)(k0 + kr) * H_ + cf * 4]);
    wl[kr][cf * 4 + 0] = v.x; wl[kr][cf * 4 + 1] = v.y;
    wl[kr][cf * 4 + 2] = v.z; wl[kr][cf * 4 + 3] = v.w;
  }
  __syncthreads();
#pragma unroll
  for (int j = 0; j < 2; ++j) {
    int s = t + 256 * j;
    int n = s >> 3, g = s & 7;
    short8 o;
#pragma unroll
    for (int i = 0; i < 8; ++i) o[i] = f2bf(wl[8 * g + i][n] * sc);
    *reinterpret_cast<short8*>(&Wt[(size_t)(mat * 64 + n) * C_ + k0 + 8 * g]) = o;
  }
}

// ---------------------------------------------------------------------------
// proj: LDS-free streaming GEMM. 512 blocks x 128 thr; each WAVE owns a
// 16-row strip x 192 cols. launch_bounds(128,1): full VGPR budget so all 24
// B-fragments + x prefetch stay live and in flight together (R3's default
// cap of 76 VGPRs serialized the L2 loads -> 64us).
// ---------------------------------------------------------------------------
__global__ __launch_bounds__(128, 1) void proj_kernel(
    const float* __restrict__ x, const short* __restrict__ Wt,
    short* __restrict__ Kp, short* __restrict__ Qp, short* __restrict__ Vt) {
  __shared__ short vls[2][16 * 66];
  const int t = threadIdx.x;
  const int w = t >> 6, lane = t & 63;
  const int l15 = lane & 15, lg = lane >> 4;
  const int strip = blockIdx.x * 2 + w;  // 0..1023
  const float* xp = &x[(size_t)(strip * 16 + l15) * C_ + lg * 8];

  f32x4 acc[12];
  const f32x4 zf = {0.f, 0.f, 0.f, 0.f};
#pragma unroll
  for (int i = 0; i < 12; ++i) acc[i] = zf;

  float4 c0 = *reinterpret_cast<const float4*>(xp);
  float4 c1 = *reinterpret_cast<const float4*>(xp + 4);
  float4 c2 = *reinterpret_cast<const float4*>(xp + 32);
  float4 c3 = *reinterpret_cast<const float4*>(xp + 36);

#pragma unroll 1
  for (int c = 0; c < 16; ++c) {
    // B fragments for this chunk: 24 independent L2 loads, all in flight
    short8 b[24];
    const int k0 = c * 64;
#pragma unroll
    for (int nt = 0; nt < 12; ++nt) {
      const short* wp = &Wt[(size_t)(16 * nt + l15) * C_ + k0 + lg * 8];
      b[2 * nt]     = *reinterpret_cast<const short8*>(wp);
      b[2 * nt + 1] = *reinterpret_cast<const short8*>(wp + 32);
    }
    // next-chunk x prefetch (HBM)
    float4 n0, n1, n2, n3;
    if (c < 15) {
      const float* xn = xp + (c + 1) * 64;
      n0 = *reinterpret_cast<const float4*>(xn);
      n1 = *reinterpret_cast<const float4*>(xn + 4);
      n2 = *reinterpret_cast<const float4*>(xn + 32);
      n3 = *reinterpret_cast<const float4*>(xn + 36);
    }
    short8 a0, a1;
    a0[0] = f2bf(c0.x); a0[1] = f2bf(c0.y); a0[2] = f2bf(c0.z); a0[3] = f2bf(c0.w);
    a0[4] = f2bf(c1.x); a0[5] = f2bf(c1.y); a0[6] = f2bf(c1.z); a0[7] = f2bf(c1.w);
    a1[0] = f2bf(c2.x); a1[1] = f2bf(c2.y); a1[2] = f2bf(c2.z); a1[3] = f2bf(c2.w);
    a1[4] = f2bf(c3.x); a1[5] = f2bf(c3.y); a1[6] = f2bf(c3.z); a1[7] = f2bf(c3.w);
#pragma unroll
    for (int nt = 0; nt < 12; ++nt) {
      acc[nt] = __builtin_amdgcn_mfma_f32_16x16x32_bf16(a0, b[2 * nt], acc[nt], 0, 0, 0);
      acc[nt] = __builtin_amdgcn_mfma_f32_16x16x32_bf16(a1, b[2 * nt + 1], acc[nt], 0, 0, 0);
    }
    if (c < 15) { c0 = n0; c1 = n1; c2 = n2; c3 = n3; }
  }

  // K, Q row-major bf16 stores (D layout: col=l15, row=lg*4+r)
  const int rb = strip * 16;
#pragma unroll
  for (int nt = 0; nt < 4; ++nt)
#pragma unroll
    for (int r = 0; r < 4; ++r) {
      const size_t orow = rb + lg * 4 + r;
      Kp[orow * H_ + nt * 16 + l15] = f2bf(acc[nt][r]);
      Qp[orow * H_ + nt * 16 + l15] = f2bf(acc[4 + nt][r]);
    }
  // Vt transpose through wave-private LDS
  short* vl = &vls[w][0];
#pragma unroll
  for (int nt = 0; nt < 4; ++nt)
#pragma unroll
    for (int r = 0; r < 4; ++r)
      vl[(lg * 4 + r) * 66 + nt * 16 + l15] = f2bf(acc[8 + nt][r]);
  asm volatile("s_waitcnt lgkmcnt(0)" ::: "memory");
  short8 o0, o1;
#pragma unroll
  for (int i = 0; i < 8; ++i) o0[i] = vl[i * 66 + lane];
#pragma unroll
  for (int i = 0; i < 8; ++i) o1[i] = vl[(8 + i) * 66 + lane];
  const int bb = strip >> 7, tb = (strip & 127) * 16;
  short* dst = &Vt[((size_t)bb * H_ + lane) * T_ + tb];
  *reinterpret_cast<short8*>(dst) = o0;
  *reinterpret_cast<short8*>(dst + 8) = o1;
}

// ---------------------------------------------------------------------------
// attn: causal flash attention, bf16 MFMA, flash-decoding k-split x4.
// 512 blocks (batch x 64 pairs) x 256 thr (4 waves). Wave s handles k-tiles
// kt = s, s+4, ... for the tile pair (u, 127-u): exactly 9 k-iters per wave.
// launch_bounds(256,1): prefetch fragments (Kc/Kn/Vc = 96 VGPRs) stay live.
// Scale 2^-5 is pre-folded into the Kp projection. Partials combined in LDS.
// ---------------------------------------------------------------------------
__global__ __launch_bounds__(256, 1) void attn_kernel(
    const short* __restrict__ Kq, const short* __restrict__ Qk,
    const short* __restrict__ Vt, float* __restrict__ out) {
  __shared__ short Ps[4][16 * 64];
  __shared__ float Po[4][16][68];
  __shared__ float Ml[4][16][2];
  const int t = threadIdx.x, s = t >> 6, lane = t & 63;
  const int l15 = lane & 15, lg = lane >> 4;
  const int batch = blockIdx.x >> 6;
  const int pr = blockIdx.x & 63;
  const short* Kb = Kq + (size_t)batch * T_ * H_;
  const short* Qb = Qk + (size_t)batch * T_ * H_;
  const short* Vb = Vt + (size_t)batch * H_ * T_;
  float* ob = out + (size_t)batch * T_ * H_;
  short* ps = &Ps[s][0];
  const f32x4 zf = {0.f, 0.f, 0.f, 0.f};

#pragma unroll 1
  for (int uu = 0; uu < 2; ++uu) {
    const int u = uu ? (127 - pr) : pr;
    const int qbase = u * 16;
    const short* qp = &Kb[(size_t)(qbase + l15) * H_ + lg * 8];
    const short8 qa0 = *reinterpret_cast<const short8*>(qp);
    const short8 qa1 = *reinterpret_cast<const short8*>(qp + 32);
    f32x4 O[4];
    float m[4], l[4];
#pragma unroll
    for (int i = 0; i < 4; ++i) { O[i] = zf; m[i] = -1e30f; l[i] = 0.f; }
    const int nkt = (u >> 2) + 1;
    const int cnt = (s < nkt) ? ((nkt - 1 - s) >> 2) + 1 : 0;
    int kt = s;

    short8 Kc[8];
    if (cnt > 0) {
#pragma unroll
      for (int nt = 0; nt < 4; ++nt) {
        const short* kp = &Qb[(size_t)(kt * 64 + 16 * nt + l15) * H_ + lg * 8];
        Kc[2 * nt]     = *reinterpret_cast<const short8*>(kp);
        Kc[2 * nt + 1] = *reinterpret_cast<const short8*>(kp + 32);
      }
    }
#pragma unroll 1
    for (int i = 0; i < cnt; ++i) {
      const int kbase = kt * 64;
      // current-V loads (used ~600cy later in PV)
      short8 Vc[8];
#pragma unroll
      for (int nt = 0; nt < 4; ++nt) {
        const short* vp = &Vb[(size_t)(16 * nt + l15) * T_ + kbase + lg * 8];
        Vc[nt]     = *reinterpret_cast<const short8*>(vp);
        Vc[4 + nt] = *reinterpret_cast<const short8*>(vp + 32);
      }
      // next-K prefetch
      short8 Kn[8];
      const bool more = (i + 1 < cnt);
      if (more) {
#pragma unroll
        for (int nt = 0; nt < 4; ++nt) {
          const short* kp =
              &Qb[(size_t)((kt + 4) * 64 + 16 * nt + l15) * H_ + lg * 8];
          Kn[2 * nt]     = *reinterpret_cast<const short8*>(kp);
          Kn[2 * nt + 1] = *reinterpret_cast<const short8*>(kp + 32);
        }
      }
      // QK^T
      f32x4 S[4];
#pragma unroll
      for (int nt = 0; nt < 4; ++nt) S[nt] = zf;
#pragma unroll
      for (int nt = 0; nt < 4; ++nt) {
        S[nt] = __builtin_amdgcn_mfma_f32_16x16x32_bf16(qa0, Kc[2 * nt], S[nt], 0, 0, 0);
        S[nt] = __builtin_amdgcn_mfma_f32_16x16x32_bf16(qa1, Kc[2 * nt + 1], S[nt], 0, 0, 0);
      }
      const bool last = (kt == nkt - 1);
      float rmax[4];
#pragma unroll
      for (int r = 0; r < 4; ++r) {
        if (last) {
#pragma unroll
          for (int nt = 0; nt < 4; ++nt)
            if (kbase + 16 * nt + l15 > qbase + lg * 4 + r) S[nt][r] = -1e30f;
        }
        float mx = fmaxf(fmaxf(S[0][r], S[1][r]), fmaxf(S[2][r], S[3][r]));
        mx = fmaxf(mx, __shfl_xor(mx, 1));
        mx = fmaxf(mx, __shfl_xor(mx, 2));
        mx = fmaxf(mx, __shfl_xor(mx, 4));
        mx = fmaxf(mx, __shfl_xor(mx, 8));
        rmax[r] = mx;
      }
#pragma unroll
      for (int r = 0; r < 4; ++r) {
        const float mn = fmaxf(m[r], rmax[r]);
        const float sc = __expf(m[r] - mn);
        m[r] = mn;
        float rs = 0.f;
#pragma unroll
        for (int nt = 0; nt < 4; ++nt) {
          const float p = __expf(S[nt][r] - mn);
          S[nt][r] = p;
          rs += p;
        }
        rs += __shfl_xor(rs, 1);
        rs += __shfl_xor(rs, 2);
        rs += __shfl_xor(rs, 4);
        rs += __shfl_xor(rs, 8);
        l[r] = l[r] * sc + rs;
#pragma unroll
        for (int nt = 0; nt < 4; ++nt) O[nt][r] *= sc;
        const int row = lg * 4 + r;
#pragma unroll
        for (int nt = 0; nt < 4; ++nt)
          ps[row * 64 + ((16 * nt + l15) ^ ((row & 7) << 3))] = f2bf(S[nt][r]);
      }
      // PV
#pragma unroll
      for (int kc = 0; kc < 2; ++kc) {
        short8 pa = *reinterpret_cast<const short8*>(
            &ps[l15 * 64 + ((kc * 32 + lg * 8) ^ ((l15 & 7) << 3))]);
#pragma unroll
        for (int nt = 0; nt < 4; ++nt)
          O[nt] = __builtin_amdgcn_mfma_f32_16x16x32_bf16(pa, Vc[kc * 4 + nt], O[nt], 0, 0, 0);
      }
      if (more) {
#pragma unroll
        for (int j = 0; j < 8; ++j) Kc[j] = Kn[j];
      }
      kt += 4;
    }
    // publish partials (unnormalized O, per-row m/l)
#pragma unroll
    for (int nt = 0; nt < 4; ++nt)
#pragma unroll
      for (int r = 0; r < 4; ++r)
        Po[s][lg * 4 + r][nt * 16 + l15] = O[nt][r];
    if (l15 == 0) {
#pragma unroll
      for (int r = 0; r < 4; ++r) {
        Ml[s][lg * 4 + r][0] = m[r];
        Ml[s][lg * 4 + r][1] = l[r];
      }
    }
    __syncthreads();
    // combine 4 partials -> output (thread t: row t>>4, f4-col t&15)
    {
      const int row = t >> 4, c4 = t & 15;
      float M = fmaxf(fmaxf(Ml[0][row][0], Ml[1][row][0]),
                      fmaxf(Ml[2][row][0], Ml[3][row][0]));
      float L = 0.f;
      f32x4 o = zf;
#pragma unroll
      for (int s2 = 0; s2 < 4; ++s2) {
        const float sc = __expf(Ml[s2][row][0] - M);
        L += Ml[s2][row][1] * sc;
        const f32x4 po = *reinterpret_cast<const f32x4*>(&Po[s2][row][c4 * 4]);
        o += po * sc;
      }
      const f32x4 res = o * (1.f / L);
      *reinterpret_cast<f32x4*>(&ob[(size_t)(qbase + row) * H_ + c4 * 4]) = res;
    }
    __syncthreads();
  }
}

extern "C" void kernel_launch(void* const* d_in, const int* in_sizes, int n_in,
                              void* d_out, int out_size, void* d_ws, size_t ws_size,
                              hipStream_t stream) {
  const float* x = (const float*)d_in[0];
  const float* Wk = (const float*)d_in[1];
  const float* Wq = (const float*)d_in[2];
  const float* Wv = (const float*)d_in[3];
  float* out = (float*)d_out;

  short* Kp = (short*)d_ws;                  // [BT][64] bf16 (queries: x@Wk, pre-scaled 2^-5)
  short* Qp = Kp + (size_t)BT_ * H_;         // [BT][64] bf16 (keys:    x@Wq)
  short* Vt = Qp + (size_t)BT_ * H_;         // [8][64][2048] bf16 (values^T)
  short* Wt = Vt + (size_t)BT_ * H_;         // [192][1024] bf16

  hipLaunchKernelGGL(prep_w, dim3(48), dim3(256), 0, stream, Wk, Wq, Wv, Wt);
  hipLaunchKernelGGL(proj_kernel, dim3(512), dim3(128), 0, stream, x, Wt, Kp, Qp, Vt);
  hipLaunchKernelGGL(attn_kernel, dim3(512), dim3(256), 0, stream, Kp, Qp, Vt, out);
}

// Round 5
// 69.546 us; speedup vs baseline: 1.4617x; 1.4617x over previous
//
#include <hip/hip_runtime.h>
#include <cstdint>

#define B_ 8
#define T_ 2048
#define C_ 1024
#define H_ 64
#define BT_ (B_ * T_)

typedef short short8 __attribute__((ext_vector_type(8)));
typedef float f32x4 __attribute__((ext_vector_type(4)));

__device__ inline short f2bf(float f) {
  uint32_t u = __float_as_uint(f);
  u += 0x7fffu + ((u >> 16) & 1u);  // RNE; inputs finite
  return (short)(u >> 16);
}

// async global->LDS, 16B per lane; LDS dest = uniform base + lane*16 (HW rule)
__device__ __forceinline__ void gl_lds16(const void* g, void* l) {
  __builtin_amdgcn_global_load_lds(
      (const __attribute__((address_space(1))) unsigned int*)g,
      (__attribute__((address_space(3))) unsigned int*)l, 16, 0, 0);
}

// ---------------------------------------------------------------------------
// prep_w: Wk/Wq/Wv [1024][64] fp32 -> Wt [192][1024] bf16 (transposed).
// Score scale 1024^-0.5 = 2^-5 folded into Wk (queries = x@Wk source quirk).
// ---------------------------------------------------------------------------
__global__ __launch_bounds__(256) void prep_w(
    const float* __restrict__ Wk, const float* __restrict__ Wq,
    const float* __restrict__ Wv, short* __restrict__ Wt) {
  __shared__ float wl[64][68];
  const int mat = blockIdx.x >> 4;
  const int kc = blockIdx.x & 15;
  const float* W = (mat == 0) ? Wk : (mat == 1) ? Wq : Wv;
  const float sc = (mat == 0) ? 0.03125f : 1.0f;
  const int t = threadIdx.x;
  const int k0 = kc * 64;
#pragma unroll
  for (int j = 0; j < 4; ++j) {
    int s = t + 256 * j;
    int kr = s >> 4, cf = s & 15;
    float4 v = *reinterpret_cast<const float4*>(&W[(size_t)(k0 + kr) * H_ + cf * 4]);
    wl[kr][cf * 4 + 0] = v.x; wl[kr][cf * 4 + 1] = v.y;
    wl[kr][cf * 4 + 2] = v.z; wl[kr][cf * 4 + 3] = v.w;
  }
  __syncthreads();
#pragma unroll
  for (int j = 0; j < 2; ++j) {
    int s = t + 256 * j;
    int n = s >> 3, g = s & 7;
    short8 o;
#pragma unroll
    for (int i = 0; i < 8; ++i) o[i] = f2bf(wl[8 * g + i][n] * sc);
    *reinterpret_cast<short8*>(&Wt[(size_t)(mat * 64 + n) * C_ + k0 + 8 * g]) = o;
  }
}

// ---------------------------------------------------------------------------
// proj: m97-style GEMM. 512 blocks x 128 thr (2 waves). Tile M=32 x N=192,
// K-step 64, double-buffered LDS staged via global_load_lds (16B) with
// pre-swizzled global source; XOR-swizzled LDS reads (2-way = free).
// x staged as fp32, converted to bf16 at fragment load. 64KB LDS -> 2
// blocks/CU pipelining across each other's barrier drains.
// ---------------------------------------------------------------------------
__global__ __launch_bounds__(128, 1) void proj_kernel(
    const float* __restrict__ x, const short* __restrict__ Wt,
    short* __restrict__ Kp, short* __restrict__ Qp, short* __restrict__ Vt) {
  __shared__ float xs[2][32 * 64];   // 8KB each: 32 rows x 16 slots(16B)
  __shared__ short ws[2][192 * 64];  // 24KB each: 192 rows x 8 slots(16B)
  const int t = threadIdx.x;
  const int w = t >> 6, lane = t & 63;
  const int l15 = lane & 15, lg = lane >> 4;
  const int rowBase = blockIdx.x * 32;

  f32x4 acc[12];
  const f32x4 zf = {0.f, 0.f, 0.f, 0.f};
#pragma unroll
  for (int i = 0; i < 12; ++i) acc[i] = zf;

  auto stage = [&](int buf, int k0) {
    // x: 8 segs of 1KB (4 rows each); wave w does segs w*4..w*4+3
#pragma unroll
    for (int j = 0; j < 4; ++j) {
      const int seg = w * 4 + j;
      const int r = seg * 4 + (lane >> 4);
      const float* g =
          &x[(size_t)(rowBase + r) * C_ + k0 + (((lane & 15) ^ (r & 7)) << 2)];
      gl_lds16(g, (char*)&xs[buf][0] + seg * 1024);
    }
    // W: 24 segs of 1KB (8 rows each); wave w does segs w*12..w*12+11
#pragma unroll
    for (int j = 0; j < 12; ++j) {
      const int seg = w * 12 + j;
      const int n = seg * 8 + (lane >> 3);
      const short* g =
          &Wt[(size_t)n * C_ + k0 + (((lane & 7) ^ (n & 7)) << 3)];
      gl_lds16(g, (char*)&ws[buf][0] + seg * 1024);
    }
  };

  stage(0, 0);

#pragma unroll 1
  for (int it = 0; it < 16; ++it) {
    __syncthreads();  // drains staging loads (vmcnt 0) + protects reuse
    const int cb = it & 1;
    if (it < 15) stage(cb ^ 1, (it + 1) * 64);
    // A fragments: fp32 from swizzled LDS -> bf16 in-register
    const int arow = 16 * w + l15;
    const int x7 = arow & 7;
    const float* xrow = &xs[cb][arow * 64];
    float4 fa = *reinterpret_cast<const float4*>(xrow + (((2 * lg) ^ x7) << 2));
    float4 fb = *reinterpret_cast<const float4*>(xrow + (((2 * lg + 1) ^ x7) << 2));
    float4 fc = *reinterpret_cast<const float4*>(xrow + (((2 * lg + 8) ^ x7) << 2));
    float4 fd = *reinterpret_cast<const float4*>(xrow + (((2 * lg + 9) ^ x7) << 2));
    short8 a0, a1;
    a0[0] = f2bf(fa.x); a0[1] = f2bf(fa.y); a0[2] = f2bf(fa.z); a0[3] = f2bf(fa.w);
    a0[4] = f2bf(fb.x); a0[5] = f2bf(fb.y); a0[6] = f2bf(fb.z); a0[7] = f2bf(fb.w);
    a1[0] = f2bf(fc.x); a1[1] = f2bf(fc.y); a1[2] = f2bf(fc.z); a1[3] = f2bf(fc.w);
    a1[4] = f2bf(fd.x); a1[5] = f2bf(fd.y); a1[6] = f2bf(fd.z); a1[7] = f2bf(fd.w);
#pragma unroll
    for (int nt = 0; nt < 12; ++nt) {
      const int n2 = 16 * nt + l15, n7 = n2 & 7;
      const short* wrow = &ws[cb][n2 * 64];
      short8 b0 = *reinterpret_cast<const short8*>(wrow + ((lg ^ n7) << 3));
      short8 b1 = *reinterpret_cast<const short8*>(wrow + (((4 + lg) ^ n7) << 3));
      acc[nt] = __builtin_amdgcn_mfma_f32_16x16x32_bf16(a0, b0, acc[nt], 0, 0, 0);
      acc[nt] = __builtin_amdgcn_mfma_f32_16x16x32_bf16(a1, b1, acc[nt], 0, 0, 0);
    }
  }

  // ---- epilogue ----
  const int strip = blockIdx.x * 2 + w;  // 16-row strip id
  const int rb = strip * 16;
#pragma unroll
  for (int nt = 0; nt < 4; ++nt)
#pragma unroll
    for (int r = 0; r < 4; ++r) {
      const size_t orow = rb + lg * 4 + r;
      Kp[orow * H_ + nt * 16 + l15] = f2bf(acc[nt][r]);
      Qp[orow * H_ + nt * 16 + l15] = f2bf(acc[4 + nt][r]);
    }
  __syncthreads();  // xs reuse for V transpose
  short* vl = reinterpret_cast<short*>(&xs[0][0]) + w * (16 * 66);
#pragma unroll
  for (int nt = 0; nt < 4; ++nt)
#pragma unroll
    for (int r = 0; r < 4; ++r)
      vl[(lg * 4 + r) * 66 + nt * 16 + l15] = f2bf(acc[8 + nt][r]);
  asm volatile("s_waitcnt lgkmcnt(0)" ::: "memory");
  short8 o0, o1;
#pragma unroll
  for (int i = 0; i < 8; ++i) o0[i] = vl[i * 66 + lane];
#pragma unroll
  for (int i = 0; i < 8; ++i) o1[i] = vl[(8 + i) * 66 + lane];
  const int bb = strip >> 7, tb = (strip & 127) * 16;
  short* dst = &Vt[((size_t)bb * H_ + lane) * T_ + tb];
  *reinterpret_cast<short8*>(dst) = o0;
  *reinterpret_cast<short8*>(dst + 8) = o1;
}

// ---------------------------------------------------------------------------
// attn: causal flash attention, bf16 MFMA, flash-decoding k-split x4.
// 512 blocks (batch x 64 pairs) x 256 thr (4 waves); wave s handles k-tiles
// kt = s, s+4, ...: exactly 9 k-iters/wave. setprio around MFMA clusters
// (independent waves at different phases -> scheduler arbitration pays, T5).
// ---------------------------------------------------------------------------
__global__ __launch_bounds__(256, 1) void attn_kernel(
    const short* __restrict__ Kq, const short* __restrict__ Qk,
    const short* __restrict__ Vt, float* __restrict__ out) {
  __shared__ short Ps[4][16 * 64];
  __shared__ float Po[4][16][68];
  __shared__ float Ml[4][16][2];
  const int t = threadIdx.x, s = t >> 6, lane = t & 63;
  const int l15 = lane & 15, lg = lane >> 4;
  const int batch = blockIdx.x >> 6;
  const int pr = blockIdx.x & 63;
  const short* Kb = Kq + (size_t)batch * T_ * H_;
  const short* Qb = Qk + (size_t)batch * T_ * H_;
  const short* Vb = Vt + (size_t)batch * H_ * T_;
  float* ob = out + (size_t)batch * T_ * H_;
  short* ps = &Ps[s][0];
  const f32x4 zf = {0.f, 0.f, 0.f, 0.f};

#pragma unroll 1
  for (int uu = 0; uu < 2; ++uu) {
    const int u = uu ? (127 - pr) : pr;
    const int qbase = u * 16;
    const short* qp = &Kb[(size_t)(qbase + l15) * H_ + lg * 8];
    const short8 qa0 = *reinterpret_cast<const short8*>(qp);
    const short8 qa1 = *reinterpret_cast<const short8*>(qp + 32);
    f32x4 O[4];
    float m[4], l[4];
#pragma unroll
    for (int i = 0; i < 4; ++i) { O[i] = zf; m[i] = -1e30f; l[i] = 0.f; }
    const int nkt = (u >> 2) + 1;
    const int cnt = (s < nkt) ? ((nkt - 1 - s) >> 2) + 1 : 0;
    int kt = s;

    short8 Kc[8];
    if (cnt > 0) {
#pragma unroll
      for (int nt = 0; nt < 4; ++nt) {
        const short* kp = &Qb[(size_t)(kt * 64 + 16 * nt + l15) * H_ + lg * 8];
        Kc[2 * nt]     = *reinterpret_cast<const short8*>(kp);
        Kc[2 * nt + 1] = *reinterpret_cast<const short8*>(kp + 32);
      }
    }
#pragma unroll 1
    for (int i = 0; i < cnt; ++i) {
      const int kbase = kt * 64;
      short8 Vc[8];
#pragma unroll
      for (int nt = 0; nt < 4; ++nt) {
        const short* vp = &Vb[(size_t)(16 * nt + l15) * T_ + kbase + lg * 8];
        Vc[nt]     = *reinterpret_cast<const short8*>(vp);
        Vc[4 + nt] = *reinterpret_cast<const short8*>(vp + 32);
      }
      short8 Kn[8];
      const bool more = (i + 1 < cnt);
      if (more) {
#pragma unroll
        for (int nt = 0; nt < 4; ++nt) {
          const short* kp =
              &Qb[(size_t)((kt + 4) * 64 + 16 * nt + l15) * H_ + lg * 8];
          Kn[2 * nt]     = *reinterpret_cast<const short8*>(kp);
          Kn[2 * nt + 1] = *reinterpret_cast<const short8*>(kp + 32);
        }
      }
      f32x4 S[4];
#pragma unroll
      for (int nt = 0; nt < 4; ++nt) S[nt] = zf;
      __builtin_amdgcn_s_setprio(1);
#pragma unroll
      for (int nt = 0; nt < 4; ++nt) {
        S[nt] = __builtin_amdgcn_mfma_f32_16x16x32_bf16(qa0, Kc[2 * nt], S[nt], 0, 0, 0);
        S[nt] = __builtin_amdgcn_mfma_f32_16x16x32_bf16(qa1, Kc[2 * nt + 1], S[nt], 0, 0, 0);
      }
      __builtin_amdgcn_s_setprio(0);
      const bool last = (kt == nkt - 1);
      float rmax[4];
#pragma unroll
      for (int r = 0; r < 4; ++r) {
        if (last) {
#pragma unroll
          for (int nt = 0; nt < 4; ++nt)
            if (kbase + 16 * nt + l15 > qbase + lg * 4 + r) S[nt][r] = -1e30f;
        }
        float mx = fmaxf(fmaxf(S[0][r], S[1][r]), fmaxf(S[2][r], S[3][r]));
        mx = fmaxf(mx, __shfl_xor(mx, 1));
        mx = fmaxf(mx, __shfl_xor(mx, 2));
        mx = fmaxf(mx, __shfl_xor(mx, 4));
        mx = fmaxf(mx, __shfl_xor(mx, 8));
        rmax[r] = mx;
      }
#pragma unroll
      for (int r = 0; r < 4; ++r) {
        const float mn = fmaxf(m[r], rmax[r]);
        const float sc = __expf(m[r] - mn);
        m[r] = mn;
        float rs = 0.f;
#pragma unroll
        for (int nt = 0; nt < 4; ++nt) {
          const float p = __expf(S[nt][r] - mn);
          S[nt][r] = p;
          rs += p;
        }
        rs += __shfl_xor(rs, 1);
        rs += __shfl_xor(rs, 2);
        rs += __shfl_xor(rs, 4);
        rs += __shfl_xor(rs, 8);
        l[r] = l[r] * sc + rs;
#pragma unroll
        for (int nt = 0; nt < 4; ++nt) O[nt][r] *= sc;
        const int row = lg * 4 + r;
#pragma unroll
        for (int nt = 0; nt < 4; ++nt)
          ps[row * 64 + ((16 * nt + l15) ^ ((row & 7) << 3))] = f2bf(S[nt][r]);
      }
      __builtin_amdgcn_s_setprio(1);
#pragma unroll
      for (int kc = 0; kc < 2; ++kc) {
        short8 pa = *reinterpret_cast<const short8*>(
            &ps[l15 * 64 + ((kc * 32 + lg * 8) ^ ((l15 & 7) << 3))]);
#pragma unroll
        for (int nt = 0; nt < 4; ++nt)
          O[nt] = __builtin_amdgcn_mfma_f32_16x16x32_bf16(pa, Vc[kc * 4 + nt], O[nt], 0, 0, 0);
      }
      __builtin_amdgcn_s_setprio(0);
      if (more) {
#pragma unroll
        for (int j = 0; j < 8; ++j) Kc[j] = Kn[j];
      }
      kt += 4;
    }
#pragma unroll
    for (int nt = 0; nt < 4; ++nt)
#pragma unroll
      for (int r = 0; r < 4; ++r)
        Po[s][lg * 4 + r][nt * 16 + l15] = O[nt][r];
    if (l15 == 0) {
#pragma unroll
      for (int r = 0; r < 4; ++r) {
        Ml[s][lg * 4 + r][0] = m[r];
        Ml[s][lg * 4 + r][1] = l[r];
      }
    }
    __syncthreads();
    {
      const int row = t >> 4, c4 = t & 15;
      float M = fmaxf(fmaxf(Ml[0][row][0], Ml[1][row][0]),
                      fmaxf(Ml[2][row][0], Ml[3][row][0]));
      float L = 0.f;
      f32x4 o = zf;
#pragma unroll
      for (int s2 = 0; s2 < 4; ++s2) {
        const float sc = __expf(Ml[s2][row][0] - M);
        L += Ml[s2][row][1] * sc;
        const f32x4 po = *reinterpret_cast<const f32x4*>(&Po[s2][row][c4 * 4]);
        o += po * sc;
      }
      const f32x4 res = o * (1.f / L);
      *reinterpret_cast<f32x4*>(&ob[(size_t)(qbase + row) * H_ + c4 * 4]) = res;
    }
    __syncthreads();
  }
}

extern "C" void kernel_launch(void* const* d_in, const int* in_sizes, int n_in,
                              void* d_out, int out_size, void* d_ws, size_t ws_size,
                              hipStream_t stream) {
  const float* x = (const float*)d_in[0];
  const float* Wk = (const float*)d_in[1];
  const float* Wq = (const float*)d_in[2];
  const float* Wv = (const float*)d_in[3];
  float* out = (float*)d_out;

  short* Kp = (short*)d_ws;                  // [BT][64] bf16 (queries: x@Wk, pre-scaled 2^-5)
  short* Qp = Kp + (size_t)BT_ * H_;         // [BT][64] bf16 (keys:    x@Wq)
  short* Vt = Qp + (size_t)BT_ * H_;         // [8][64][2048] bf16 (values^T)
  short* Wt = Vt + (size_t)BT_ * H_;         // [192][1024] bf16

  hipLaunchKernelGGL(prep_w, dim3(48), dim3(256), 0, stream, Wk, Wq, Wv, Wt);
  hipLaunchKernelGGL(proj_kernel, dim3(512), dim3(128), 0, stream, x, Wt, Kp, Qp, Vt);
  hipLaunchKernelGGL(attn_kernel, dim3(512), dim3(256), 0, stream, Kp, Qp, Vt, out);
}